// Round 3
// baseline (489.573 us; speedup 1.0000x reference)
//
#include <hip/hip_runtime.h>

#define NUSERS 100000
#define NITEMS 50000
#define NNODES (NUSERS + NITEMS)
#define DIM 64
#define NEDGE 2000000

// bucketed CSR build
#define BSH 7                       // 128 dst nodes per csr bucket
#define NB ((NNODES + 127) >> BSH)  // 1172 buckets
#define CAP 2048                    // hard per-bucket cap (csr clamps to this)
#define CHUNK 2048                  // edges per bucket_kernel block
#define ABLOCKS ((NEDGE + CHUNK - 1) / CHUNK)  // 977

// pull blocks: 64-node half-buckets; edge count per half-bucket <= CAP (hard)
#define NPB 64
#define PB ((NNODES + NPB - 1) / NPB)          // 2344
#define NPW 16                                  // nodes per wave

// ---------------------------------------------------------------------------
// Phase A: block-level counting sort of a 2048-edge chunk into 1172 coarse
// dst-buckets (dst>>7). Record = 8B: (src | (dst&127)<<18, w_bits).
// Per-bucket runs reserved with one global atomic per (block, nonzero bucket),
// staged in LDS, written out coalesced.
// ---------------------------------------------------------------------------
__global__ __launch_bounds__(256)
void bucket_kernel(const int* __restrict__ eidx, const float* __restrict__ ew,
                   int* __restrict__ gcur, int2* __restrict__ regions) {
    __shared__ int cursor_s[NB];          // histogram, then LDS staging cursor
    __shared__ int excl_s[NB];            // block-local exclusive offsets
    __shared__ int gbase_s[NB];           // reserved base inside bucket region
    __shared__ int scanbuf[256];
    __shared__ int2 stage[CHUNK];         // 16 KB
    __shared__ unsigned short sbkt[CHUNK];// 4 KB

    const int t = threadIdx.x;
    const int e0 = blockIdx.x * CHUNK;
    const int cnt_edges = min(CHUNK, NEDGE - e0);   // always multiple of 4

    for (int i = t; i < NB; i += 256) cursor_s[i] = 0;
    __syncthreads();

    // pass 1: load 8 edges/thread (int4/float4 coalesced), LDS histogram
    int2 recs[8];
    int bk[8];
    const int e4base = e0 >> 2;
#pragma unroll
    for (int k = 0; k < 2; ++k) {
        int g = k * 256 + t;                       // 4-edge group within chunk
        bool ok = (4 * g) < cnt_edges;
        int4 s4 = make_int4(0, 0, 0, 0), d4 = make_int4(0, 0, 0, 0);
        float4 w4 = make_float4(0.f, 0.f, 0.f, 0.f);
        if (ok) {
            int e4 = e4base + g;
            s4 = ((const int4*)eidx)[e4];
            d4 = ((const int4*)eidx)[(NEDGE >> 2) + e4];
            w4 = ((const float4*)ew)[e4];
        }
        int ss[4] = {s4.x, s4.y, s4.z, s4.w};
        int dd[4] = {d4.x, d4.y, d4.z, d4.w};
        float ww[4] = {w4.x, w4.y, w4.z, w4.w};
#pragma unroll
        for (int j = 0; j < 4; ++j) {
            int idx = 4 * k + j;
            if (ok) {
                int d = dd[j];
                int b = d >> BSH;
                bk[idx] = b;
                recs[idx].x = ss[j] | ((d & 127) << 18);   // src < 2^18
                recs[idx].y = __float_as_int(ww[j]);
                atomicAdd(&cursor_s[b], 1);
            } else {
                bk[idx] = -1;
            }
        }
    }
    __syncthreads();

    // block scan of the 1172 counts; thread t owns [5t, 5t+5)
    int myv[5];
    int tsum = 0;
    const int base_i = t * 5;
#pragma unroll
    for (int j = 0; j < 5; ++j) {
        int i = base_i + j;
        myv[j] = (i < NB) ? cursor_s[i] : 0;
        tsum += myv[j];
    }
    scanbuf[t] = tsum;
    __syncthreads();
    for (int d = 1; d < 256; d <<= 1) {
        int u = (t >= d) ? scanbuf[t - d] : 0;
        __syncthreads();
        scanbuf[t] += u;
        __syncthreads();
    }
    int run = scanbuf[t] - tsum;   // exclusive base of this thread's range
#pragma unroll
    for (int j = 0; j < 5; ++j) {
        int i = base_i + j;
        if (i < NB) {
            excl_s[i] = run;
            cursor_s[i] = run;     // becomes staging cursor
            if (myv[j] > 0) gbase_s[i] = atomicAdd(&gcur[i], myv[j]);
            run += myv[j];
        }
    }
    __syncthreads();

    // pass 2: counting-sort into LDS staging
#pragma unroll
    for (int k = 0; k < 8; ++k) {
        if (bk[k] >= 0) {
            int p = atomicAdd(&cursor_s[bk[k]], 1);
            stage[p] = recs[k];
            sbkt[p] = (unsigned short)bk[k];
        }
    }
    __syncthreads();

    // pass 3: coalesced write-out of per-bucket runs
    for (int i = t; i < cnt_edges; i += 256) {
        int b = sbkt[i];
        int gpos = gbase_s[b] + (i - excl_s[b]);
        if (gpos < CAP) regions[(long)b * CAP + gpos] = stage[i];
    }
}

// ---------------------------------------------------------------------------
// exclusive scan of the 1172 bucket counts -> per-bucket base in edge_packed.
// ---------------------------------------------------------------------------
__global__ void bucket_scan_kernel(const int* __restrict__ gcur, int* __restrict__ bbase,
                                   int* __restrict__ row_start) {
    __shared__ int scanbuf[256];
    const int t = threadIdx.x;
    int myv[5];
    int tsum = 0;
#pragma unroll
    for (int j = 0; j < 5; ++j) {
        int i = t * 5 + j;
        myv[j] = (i < NB) ? min(gcur[i], CAP) : 0;
        tsum += myv[j];
    }
    scanbuf[t] = tsum;
    __syncthreads();
    for (int d = 1; d < 256; d <<= 1) {
        int u = (t >= d) ? scanbuf[t - d] : 0;
        __syncthreads();
        scanbuf[t] += u;
        __syncthreads();
    }
    int run = scanbuf[t] - tsum;
#pragma unroll
    for (int j = 0; j < 5; ++j) {
        int i = t * 5 + j;
        if (i < NB) { bbase[i] = run; run += myv[j]; }
    }
    if (t == 0) row_start[NNODES] = NEDGE;
}

// ---------------------------------------------------------------------------
// Phase B: one block per bucket -> exact row_start + contiguous edge_packed.
// ---------------------------------------------------------------------------
__global__ __launch_bounds__(256)
void csr_kernel(const int2* __restrict__ regions, const int* __restrict__ gcur,
                const int* __restrict__ bbase, int* __restrict__ row_start,
                int2* __restrict__ edge_packed) {
    __shared__ int cnt[128];      // per-dst count, then cursor
    __shared__ int excl[128];
    __shared__ int scanbuf[256];
    const int t = threadIdx.x;
    const int b = blockIdx.x;
    const int nb = min(gcur[b], CAP);
    const int base = bbase[b];

    if (t < 128) cnt[t] = 0;
    __syncthreads();

    int2 recs[8];
#pragma unroll
    for (int k = 0; k < 8; ++k) {
        int i = k * 256 + t;
        if (i < nb) {
            recs[k] = regions[(long)b * CAP + i];
            atomicAdd(&cnt[recs[k].x >> 18], 1);
        }
    }
    __syncthreads();

    scanbuf[t] = (t < 128) ? cnt[t] : 0;
    int v = scanbuf[t];
    __syncthreads();
    for (int d = 1; d < 256; d <<= 1) {
        int u = (t >= d) ? scanbuf[t - d] : 0;
        __syncthreads();
        scanbuf[t] += u;
        __syncthreads();
    }
    if (t < 128) {
        excl[t] = scanbuf[t] - v;
        int node = (b << BSH) + t;
        if (node < NNODES) row_start[node] = base + excl[t];
    }
    __syncthreads();
    if (t < 128) cnt[t] = excl[t];    // cnt becomes cursor
    __syncthreads();

#pragma unroll
    for (int k = 0; k < 8; ++k) {
        int i = k * 256 + t;
        if (i < nb) {
            int d = recs[k].x >> 18;
            int p = base + atomicAdd(&cnt[d], 1);
            int2 orec;
            orec.x = recs[k].x & 0x3FFFF;   // clean src
            orec.y = recs[k].y;
            edge_packed[p] = orec;
        }
    }
}

// ---------------------------------------------------------------------------
// pull layer 1: one block per 64-node half-bucket. Edge records staged in LDS
// (coalesced; count hard-bounded by CAP), row_start slice in LDS -> the only
// global round per node is the gather itself, 8-wide unrolled. Gathers read
// straight from eu/eit (buf0 never materialized). Fused ReLU.
// ---------------------------------------------------------------------------
__global__ __launch_bounds__(256)
void pull1_kernel(const int* __restrict__ row_start,
                  const int2* __restrict__ edge_packed,
                  const float* __restrict__ eu, const float* __restrict__ eit,
                  float* __restrict__ out_emb) {
    __shared__ int2 erec[CAP];        // 16 KB
    __shared__ int rs[NPB + 1];
    const int t = threadIdx.x;
    const int node0 = blockIdx.x * NPB;

    for (int i = t; i <= NPB; i += 256) {
        int node = node0 + i;
        rs[i] = row_start[node > NNODES ? NNODES : node];
    }
    __syncthreads();
    const int ebase = rs[0];
    const int ecnt = rs[NPB] - ebase;          // <= CAP (hard, via csr clamp)
    for (int i = t; i < ecnt; i += 256) erec[i] = edge_packed[ebase + i];
    __syncthreads();

    const int lane = t & 63;
    const int wv = t >> 6;
    for (int j = 0; j < NPW; ++j) {
        const int local = wv * NPW + j;
        const int node = node0 + local;
        if (node >= NNODES) break;             // wave-uniform
        int i = rs[local] - ebase;
        const int iend = rs[local + 1] - ebase;
        float a0 = 0.f, a1 = 0.f, a2 = 0.f, a3 = 0.f;
        for (; i + 7 < iend; i += 8) {
            int2 r0 = erec[i + 0], r1 = erec[i + 1], r2 = erec[i + 2], r3 = erec[i + 3];
            int2 r4 = erec[i + 4], r5 = erec[i + 5], r6 = erec[i + 6], r7 = erec[i + 7];
            const float* p0 = (r0.x < NUSERS) ? (eu + (r0.x << 6)) : (eit + ((r0.x - NUSERS) << 6));
            const float* p1 = (r1.x < NUSERS) ? (eu + (r1.x << 6)) : (eit + ((r1.x - NUSERS) << 6));
            const float* p2 = (r2.x < NUSERS) ? (eu + (r2.x << 6)) : (eit + ((r2.x - NUSERS) << 6));
            const float* p3 = (r3.x < NUSERS) ? (eu + (r3.x << 6)) : (eit + ((r3.x - NUSERS) << 6));
            const float* p4 = (r4.x < NUSERS) ? (eu + (r4.x << 6)) : (eit + ((r4.x - NUSERS) << 6));
            const float* p5 = (r5.x < NUSERS) ? (eu + (r5.x << 6)) : (eit + ((r5.x - NUSERS) << 6));
            const float* p6 = (r6.x < NUSERS) ? (eu + (r6.x << 6)) : (eit + ((r6.x - NUSERS) << 6));
            const float* p7 = (r7.x < NUSERS) ? (eu + (r7.x << 6)) : (eit + ((r7.x - NUSERS) << 6));
            float v0 = p0[lane], v1 = p1[lane], v2 = p2[lane], v3 = p3[lane];
            float v4 = p4[lane], v5 = p5[lane], v6 = p6[lane], v7 = p7[lane];
            a0 = fmaf(__int_as_float(r0.y), v0, a0);
            a1 = fmaf(__int_as_float(r1.y), v1, a1);
            a2 = fmaf(__int_as_float(r2.y), v2, a2);
            a3 = fmaf(__int_as_float(r3.y), v3, a3);
            a0 = fmaf(__int_as_float(r4.y), v4, a0);
            a1 = fmaf(__int_as_float(r5.y), v5, a1);
            a2 = fmaf(__int_as_float(r6.y), v6, a2);
            a3 = fmaf(__int_as_float(r7.y), v7, a3);
        }
        for (; i + 3 < iend; i += 4) {
            int2 r0 = erec[i + 0], r1 = erec[i + 1], r2 = erec[i + 2], r3 = erec[i + 3];
            const float* p0 = (r0.x < NUSERS) ? (eu + (r0.x << 6)) : (eit + ((r0.x - NUSERS) << 6));
            const float* p1 = (r1.x < NUSERS) ? (eu + (r1.x << 6)) : (eit + ((r1.x - NUSERS) << 6));
            const float* p2 = (r2.x < NUSERS) ? (eu + (r2.x << 6)) : (eit + ((r2.x - NUSERS) << 6));
            const float* p3 = (r3.x < NUSERS) ? (eu + (r3.x << 6)) : (eit + ((r3.x - NUSERS) << 6));
            a0 = fmaf(__int_as_float(r0.y), p0[lane], a0);
            a1 = fmaf(__int_as_float(r1.y), p1[lane], a1);
            a2 = fmaf(__int_as_float(r2.y), p2[lane], a2);
            a3 = fmaf(__int_as_float(r3.y), p3[lane], a3);
        }
        for (; i < iend; ++i) {
            int2 r = erec[i];
            const float* p = (r.x < NUSERS) ? (eu + (r.x << 6)) : (eit + ((r.x - NUSERS) << 6));
            a0 = fmaf(__int_as_float(r.y), p[lane], a0);
        }
        out_emb[(long)node * DIM + lane] = fmaxf((a0 + a1) + (a2 + a3), 0.f);
    }
}

// ---------------------------------------------------------------------------
// pull layer 2 + fused epilogue: same bucket-pull structure gathering buf1;
// then per node: e2 = relu(acc); x = (e0 + e1 + e2)/3; y = x @ W^T + b via
// W rows in 64 VGPRs/lane + wave-local LDS broadcast of x; writes final row
// AND the pass-through copy row (e0). Kills final_kernel, init_kernel, buf2.
// ---------------------------------------------------------------------------
__global__ __launch_bounds__(256)
void pull2_final_kernel(const int* __restrict__ row_start,
                        const int2* __restrict__ edge_packed,
                        const float* __restrict__ buf1,
                        const float* __restrict__ eu, const float* __restrict__ eit,
                        const float* __restrict__ W, const float* __restrict__ bias,
                        float* __restrict__ out) {
    __shared__ int2 erec[CAP];        // 16 KB
    __shared__ int rs[NPB + 1];
    __shared__ float xrow[4][64];     // per-wave staging of the acc row
    const int t = threadIdx.x;
    const int lane = t & 63;
    const int wv = t >> 6;
    const int node0 = blockIdx.x * NPB;

    // W row for this lane -> 64 VGPRs
    float wreg[64];
#pragma unroll
    for (int k = 0; k < 16; ++k) {
        float4 wq = ((const float4*)(W + (lane << 6)))[k];
        wreg[4 * k + 0] = wq.x; wreg[4 * k + 1] = wq.y;
        wreg[4 * k + 2] = wq.z; wreg[4 * k + 3] = wq.w;
    }
    const float bj = bias[lane];

    for (int i = t; i <= NPB; i += 256) {
        int node = node0 + i;
        rs[i] = row_start[node > NNODES ? NNODES : node];
    }
    __syncthreads();
    const int ebase = rs[0];
    const int ecnt = rs[NPB] - ebase;
    for (int i = t; i < ecnt; i += 256) erec[i] = edge_packed[ebase + i];
    __syncthreads();

    for (int j = 0; j < NPW; ++j) {
        const int local = wv * NPW + j;
        const int node = node0 + local;
        if (node >= NNODES) break;             // wave-uniform
        int i = rs[local] - ebase;
        const int iend = rs[local + 1] - ebase;
        float a0 = 0.f, a1 = 0.f, a2 = 0.f, a3 = 0.f;
        for (; i + 7 < iend; i += 8) {
            int2 r0 = erec[i + 0], r1 = erec[i + 1], r2 = erec[i + 2], r3 = erec[i + 3];
            int2 r4 = erec[i + 4], r5 = erec[i + 5], r6 = erec[i + 6], r7 = erec[i + 7];
            float v0 = buf1[(r0.x << 6) + lane], v1 = buf1[(r1.x << 6) + lane];
            float v2 = buf1[(r2.x << 6) + lane], v3 = buf1[(r3.x << 6) + lane];
            float v4 = buf1[(r4.x << 6) + lane], v5 = buf1[(r5.x << 6) + lane];
            float v6 = buf1[(r6.x << 6) + lane], v7 = buf1[(r7.x << 6) + lane];
            a0 = fmaf(__int_as_float(r0.y), v0, a0);
            a1 = fmaf(__int_as_float(r1.y), v1, a1);
            a2 = fmaf(__int_as_float(r2.y), v2, a2);
            a3 = fmaf(__int_as_float(r3.y), v3, a3);
            a0 = fmaf(__int_as_float(r4.y), v4, a0);
            a1 = fmaf(__int_as_float(r5.y), v5, a1);
            a2 = fmaf(__int_as_float(r6.y), v6, a2);
            a3 = fmaf(__int_as_float(r7.y), v7, a3);
        }
        for (; i + 3 < iend; i += 4) {
            int2 r0 = erec[i + 0], r1 = erec[i + 1], r2 = erec[i + 2], r3 = erec[i + 3];
            a0 = fmaf(__int_as_float(r0.y), buf1[(r0.x << 6) + lane], a0);
            a1 = fmaf(__int_as_float(r1.y), buf1[(r1.x << 6) + lane], a1);
            a2 = fmaf(__int_as_float(r2.y), buf1[(r2.x << 6) + lane], a2);
            a3 = fmaf(__int_as_float(r3.y), buf1[(r3.x << 6) + lane], a3);
        }
        for (; i < iend; ++i) {
            int2 r = erec[i];
            a0 = fmaf(__int_as_float(r.y), buf1[(r.x << 6) + lane], a0);
        }
        float e2v = fmaxf((a0 + a1) + (a2 + a3), 0.f);

        // e0 (original emb) + e1 (layer-1) rows, coalesced
        const float* e0p = (node < NUSERS) ? (eu + ((long)node << 6))
                                           : (eit + ((long)(node - NUSERS) << 6));
        float e0v = e0p[lane];
        float e1v = buf1[((long)node << 6) + lane];
        float x = (e0v + e1v + e2v) * (1.0f / 3.0f);

        // wave-local GEMM: stage x row, broadcast-read, FMA with wreg
        xrow[wv][lane] = x;
        const float4* xr = (const float4*)xrow[wv];
        float s0 = 0.f, s1 = 0.f;
#pragma unroll
        for (int k = 0; k < 16; ++k) {
            float4 v = xr[k];                   // same-address broadcast
            s0 = fmaf(v.x, wreg[4 * k + 0], s0);
            s1 = fmaf(v.y, wreg[4 * k + 1], s1);
            s0 = fmaf(v.z, wreg[4 * k + 2], s0);
            s1 = fmaf(v.w, wreg[4 * k + 3], s1);
        }
        float val = s0 + s1 + bj;

        long fo, co;
        if (node < NUSERS) {
            fo = (long)node * DIM;
            co = fo + (long)NUSERS * DIM;
        } else {
            fo = (long)2 * NUSERS * DIM + (long)(node - NUSERS) * DIM;
            co = fo + (long)NITEMS * DIM;
        }
        out[fo + lane] = val;
        out[co + lane] = e0v;                   // pass-through copy
    }
}

extern "C" void kernel_launch(void* const* d_in, const int* in_sizes, int n_in,
                              void* d_out, int out_size, void* d_ws, size_t ws_size,
                              hipStream_t stream) {
    const int*   eidx = (const int*)d_in[0];     // (2, E) int
    const float* ew   = (const float*)d_in[1];   // (E,)
    const float* eu   = (const float*)d_in[2];   // (NUSERS, 64)
    const float* eit  = (const float*)d_in[3];   // (NITEMS, 64)
    const float* W    = (const float*)d_in[4];   // (64, 64)
    const float* bias = (const float*)d_in[5];   // (64,)
    float* out = (float*)d_out;

    const size_t nfeat = (size_t)NNODES * DIM;   // 9.6M floats
    float* buf1        = (float*)d_ws;                       // 38.4 MB
    int2*  edge_packed = (int2*)(buf1 + nfeat);              // 16 MB
    int*   row_start   = (int*)(edge_packed + NEDGE);        // NNODES+1
    int*   gcur        = row_start + NNODES + 4;
    int*   bbase       = gcur + NB;
    int2*  regions     = (int2*)(bbase + NB + 3);            // 19.2 MB

    const int tpb = 256;

    hipMemsetAsync(gcur, 0, NB * sizeof(int), stream);

    // bucketed CSR build
    bucket_kernel<<<ABLOCKS, tpb, 0, stream>>>(eidx, ew, gcur, regions);
    bucket_scan_kernel<<<1, tpb, 0, stream>>>(gcur, bbase, row_start);
    csr_kernel<<<NB, tpb, 0, stream>>>(regions, gcur, bbase, row_start, edge_packed);

    // layer 1 (gathers straight from eu/eit, fused relu)
    pull1_kernel<<<PB, tpb, 0, stream>>>(row_start, edge_packed, eu, eit, buf1);
    // layer 2 + epilogue GEMM + pass-through copies (init/final kernels gone)
    pull2_final_kernel<<<PB, tpb, 0, stream>>>(row_start, edge_packed, buf1,
                                               eu, eit, W, bias, out);
}